// Round 7
// baseline (1262.415 us; speedup 1.0000x reference)
//
#include <hip/hip_runtime.h>
#include <stdint.h>

#define NN     6258
#define IMG_N  1600
#define CNN_N  4608
#define OUT_N  50
#define BATCH  64
#define G0SZ   1650
#define G1SZ   4608
#define IMGW   40
#define NPATCH 12
#define NB     256   // fused-kernel blocks; 4 waves + ~5 KB LDS each -> all co-resident

// ---------------- threefry2x32-20, exactly as jax/_src/prng.py ----------------
__host__ __device__ inline void tf2x32(uint32_t k0, uint32_t k1,
                                       uint32_t x0, uint32_t x1,
                                       uint32_t& o0, uint32_t& o1) {
    uint32_t ks[3] = {k0, k1, k0 ^ k1 ^ 0x1BD11BDAu};
    const int rotA[4] = {13, 15, 26, 6};
    const int rotB[4] = {17, 29, 16, 24};
    x0 += ks[0];
    x1 += ks[1];
#pragma unroll
    for (int i = 0; i < 5; ++i) {
        const int* rot = (i & 1) ? rotB : rotA;
#pragma unroll
        for (int j = 0; j < 4; ++j) {
            x0 += x1;
            x1 = (x1 << rot[j]) | (x1 >> (32 - rot[j]));
            x1 ^= x0;
        }
        x0 += ks[(i + 1) % 3];
        x1 += ks[(i + 2) % 3] + (uint32_t)(i + 1);
    }
    o0 = x0;
    o1 = x1;
}

// jax.random.uniform(...)*2-1, partitionable threefry: bits[j] = xor-fold of
// threefry(key, (0, j)).
__device__ inline float jax_uniform_pm1(uint32_t k0, uint32_t k1, uint32_t j) {
    uint32_t o0, o1;
    tf2x32(k0, k1, 0u, j, o0, o1);
    uint32_t bits = o0 ^ o1;
    float f = __uint_as_float((bits >> 9) | 0x3f800000u); // [1,2)
    return (f - 1.0f) * 2.0f - 1.0f;                      // [-1,1)
}

// XLA's f32 tanh rational approximation, non-contracted f32 ops.
__device__ inline float tanh_xla_f32(float x) {
    if (fabsf(x) < 0.0004f) return x;
    float xc = fminf(fmaxf(x, -9.0f), 9.0f);
    float x2 = __fmul_rn(xc, xc);
    float num = -2.76076847742355e-16f;
    num = __fadd_rn(__fmul_rn(num, x2), 2.00018790482477e-13f);
    num = __fadd_rn(__fmul_rn(num, x2), -8.60467152213735e-11f);
    num = __fadd_rn(__fmul_rn(num, x2), 5.12229709037114e-08f);
    num = __fadd_rn(__fmul_rn(num, x2), 1.48572235717979e-05f);
    num = __fadd_rn(__fmul_rn(num, x2), 6.37261928875436e-04f);
    num = __fadd_rn(__fmul_rn(num, x2), 4.89352455891786e-03f);
    num = __fmul_rn(num, xc);
    float den = 1.19825839466702e-06f;
    den = __fadd_rn(__fmul_rn(den, x2), 1.18534705686654e-04f);
    den = __fadd_rn(__fmul_rn(den, x2), 2.26843463243900e-03f);
    den = __fadd_rn(__fmul_rn(den, x2), 4.89352518554385e-03f);
    return __fdiv_rn(num, den);
}

__device__ inline float gibbs_decide(double acc, float h, float u) {
    float I32 = (float)(acc + (double)h);
    float t = tanh_xla_f32(I32);
    float d = __fadd_rn(t, -u);
    return (d > 0.0f) ? 1.0f : ((d < 0.0f) ? -1.0f : 0.0f);
}

struct SweepKeys { uint32_t v[16]; };  // [s]: k0a,k0b,k1a,k1b

// Barrier words live in d_out[0] (bar) and d_out[64] (gen): memory we provably
// own; overwritten with real outputs by t_out after the final barrier.
__global__ __launch_bounds__(64) void zinit(uint32_t* p) {
    if (threadIdx.x == 0) { p[0] = 0u; p[64] = 0u; }
}

// Device-scope grid barrier (monotone generation counter).
__device__ __forceinline__ void grid_sync(uint32_t* bar, uint32_t* gen) {
    __syncthreads();
    if (threadIdx.x == 0) {
        uint32_t g = __hip_atomic_load(gen, __ATOMIC_ACQUIRE, __HIP_MEMORY_SCOPE_AGENT);
        __threadfence();  // release this block's writes (L2 wb) to agent scope
        uint32_t arr = __hip_atomic_fetch_add(bar, 1u, __ATOMIC_ACQ_REL,
                                              __HIP_MEMORY_SCOPE_AGENT);
        if (arr == (uint32_t)(NB - 1)) {
            __hip_atomic_store(bar, 0u, __ATOMIC_RELAXED, __HIP_MEMORY_SCOPE_AGENT);
            __hip_atomic_fetch_add(gen, 1u, __ATOMIC_RELEASE, __HIP_MEMORY_SCOPE_AGENT);
        } else {
            while (__hip_atomic_load(gen, __ATOMIC_ACQUIRE,
                                     __HIP_MEMORY_SCOPE_AGENT) == g)
                __builtin_amdgcn_s_sleep(1);
        }
        __threadfence();  // acquire: invalidate L1/stale L2 before reading peers' writes
    }
    __syncthreads();
}

__global__ __launch_bounds__(256) void fused(const float* __restrict__ m_in,
                                             const float* __restrict__ J,
                                             const float* __restrict__ H,
                                             float* __restrict__ m_out,
                                             float* __restrict__ mt,
                                             SweepKeys keys) {
    uint32_t* bar = (uint32_t*)m_out;
    uint32_t* gen = bar + 64;
    __shared__ float  jc[800];      // J_CNN closure: jc[f*25+pos]
    __shared__ double red[4][64];
    const int tid  = (int)threadIdx.x;
    const int blk  = (int)blockIdx.x;
    const int lane = tid & 63;                 // lane = batch b
    const int wave = tid >> 6;
    const int gwid = blk * 4 + wave;           // 0..1023

    // ---- phase T_in: mt[node][b] = m[b][node]; stage closure into LDS ----
    for (int t = blk * 256 + tid; t < NN * BATCH; t += NB * 256)
        mt[t] = m_in[(size_t)(t & 63) * NN + (t >> 6)];
    for (int t = tid; t < 800; t += 256) {     // FIX: was `if (tid < 800)` -> jc[256..799] garbage
        int f = t / 25, pos = t % 25;
        jc[t] = J[(size_t)(IMG_N + f * 144) * NN + (pos / 5) * IMGW + (pos % 5)];
    }
    grid_sync(bar, gen);

    for (int s = 0; s < 4; ++s) {
        const uint32_t k0a = keys.v[s * 4 + 0], k0b = keys.v[s * 4 + 1];
        const uint32_t k1a = keys.v[s * 4 + 2], k1b = keys.v[s * 4 + 3];

        // ---- g0: blocks 0..49 -> out nodes; blocks 50..255 -> img pixels ----
        if (blk < 50) {
            const int o = blk;
            const float* Jrow = J + (size_t)(IMG_N + CNN_N + o) * NN + IMG_N;
            double a0 = 0.0, a1 = 0.0;
            const int k0i = wave * 1152;
#pragma unroll 4
            for (int k = 0; k < 1152; k += 2) {
                a0 += (double)Jrow[k0i + k]     * (double)mt[(IMG_N + k0i + k) * 64 + lane];
                a1 += (double)Jrow[k0i + k + 1] * (double)mt[(IMG_N + k0i + k + 1) * 64 + lane];
            }
            red[wave][lane] = a0 + a1;
            __syncthreads();
            if (wave == 0) {
                double a = ((red[0][lane] + red[1][lane]) + red[2][lane]) + red[3][lane];
                float u = jax_uniform_pm1(k0a, k0b, (uint32_t)(lane * G0SZ + IMG_N + o));
                mt[(IMG_N + CNN_N + o) * 64 + lane] =
                    gibbs_decide(a, H[IMG_N + CNN_N + o], u);
            }
        } else {
            const int iw = (blk - 50) * 4 + wave;  // 0..823
            for (int g = iw; g < IMG_N; g += 824) {
                int r = g / IMGW, c = g % IMGW;
                int pr_lo = (r >= 4) ? (r - 2) / 3 : 0;
                int pr_hi = r / 3; if (pr_hi > NPATCH - 1) pr_hi = NPATCH - 1;
                int pc_lo = (c >= 4) ? (c - 2) / 3 : 0;
                int pc_hi = c / 3; if (pc_hi > NPATCH - 1) pc_hi = NPATCH - 1;
                double acc = 0.0;
                for (int pr = pr_lo; pr <= pr_hi; ++pr) {
                    for (int pc = pc_lo; pc <= pc_hi; ++pc) {
                        int pos = (r - 3 * pr) * 5 + (c - 3 * pc);
                        int node0 = IMG_N + pr * NPATCH + pc;
#pragma unroll
                        for (int f = 0; f < 32; ++f)
                            acc += (double)jc[f * 25 + pos] *
                                   (double)mt[(node0 + f * 144) * 64 + lane];
                    }
                }
                float u = jax_uniform_pm1(k0a, k0b, (uint32_t)(lane * G0SZ + g));
                mt[g * 64 + lane] = gibbs_decide(acc, H[g], u);
            }
        }
        grid_sync(bar, gen);

        // ---- g1: cnn nodes, wave-stride ----
        for (int cn = gwid; cn < CNN_N; cn += NB * 4) {
            int f = cn / 144;
            int p = cn - f * 144;
            int pr = p / NPATCH, pc = p - pr * NPATCH;
            int r0 = pr * 3, c0 = pc * 3;
            double acc = 0.0;
#pragma unroll
            for (int a = 0; a < 5; ++a) {
                int rowbase = (r0 + a) * IMGW + c0;
#pragma unroll
                for (int bb = 0; bb < 5; ++bb)
                    acc += (double)jc[f * 25 + a * 5 + bb] *
                           (double)mt[(rowbase + bb) * 64 + lane];
            }
            const float* Jo = J + (size_t)(IMG_N + cn) * NN + IMG_N + CNN_N;
#pragma unroll 10
            for (int o = 0; o < OUT_N; ++o)
                acc += (double)Jo[o] * (double)mt[(IMG_N + CNN_N + o) * 64 + lane];
            float u = jax_uniform_pm1(k1a, k1b, (uint32_t)(lane * G1SZ + cn));
            mt[(IMG_N + cn) * 64 + lane] = gibbs_decide(acc, H[IMG_N + cn], u);
        }
        grid_sync(bar, gen);
    }

    // ---- T_out: m_out[b][node] = mt[node][b] (overwrites barrier words too) ----
    for (int t = blk * 256 + tid; t < NN * BATCH; t += NB * 256) {
        int b = t / NN, node = t - b * NN;
        m_out[t] = mt[node * 64 + b];
    }
}

extern "C" void kernel_launch(void* const* d_in, const int* in_sizes, int n_in,
                              void* d_out, int out_size, void* d_ws, size_t ws_size,
                              hipStream_t stream) {
    const float* m_in = (const float*)d_in[0];
    const float* J    = (const float*)d_in[1];
    const float* H    = (const float*)d_in[2];
    float* m_out = (float*)d_out;
    float* mt    = (float*)d_ws;  // [NN][64], 1.6 MB (ws_size proven >= this)

    // partitionable key chain: keys = split(key(1),4): keys[i]=threefry((0,1),(0,i))
    uint32_t K[4][2];
    for (int i = 0; i < 4; ++i)
        tf2x32(0u, 1u, 0u, (uint32_t)i, K[i][0], K[i][1]);
    SweepKeys keys;
    for (int s = 0; s < 4; ++s) {
        uint32_t k0a, k0b, k1a, k1b;
        tf2x32(K[s][0], K[s][1], 0u, 0u, k0a, k0b);  // k0 = split(keys[s])[0]
        tf2x32(K[s][0], K[s][1], 0u, 1u, k1a, k1b);  // k1 = split(keys[s])[1]
        keys.v[s * 4 + 0] = k0a; keys.v[s * 4 + 1] = k0b;
        keys.v[s * 4 + 2] = k1a; keys.v[s * 4 + 3] = k1b;
    }

    zinit<<<1, 64, 0, stream>>>((uint32_t*)d_out);
    fused<<<NB, 256, 0, stream>>>(m_in, J, H, m_out, mt, keys);
}

// Round 8
// 459.099 us; speedup vs baseline: 2.7498x; 2.7498x over previous
//
#include <hip/hip_runtime.h>
#include <stdint.h>

#define NN     6258
#define IMG_N  1600
#define CNN_N  4608
#define OUT_N  50
#define BATCH  64
#define G0SZ   1650
#define G1SZ   4608
#define IMGW   40
#define NPATCH 12
#define NB     256   // fused-kernel blocks; 4 waves + ~6 KB LDS each -> all co-resident

// ---------------- threefry2x32-20, exactly as jax/_src/prng.py ----------------
__host__ __device__ inline void tf2x32(uint32_t k0, uint32_t k1,
                                       uint32_t x0, uint32_t x1,
                                       uint32_t& o0, uint32_t& o1) {
    uint32_t ks[3] = {k0, k1, k0 ^ k1 ^ 0x1BD11BDAu};
    const int rotA[4] = {13, 15, 26, 6};
    const int rotB[4] = {17, 29, 16, 24};
    x0 += ks[0];
    x1 += ks[1];
#pragma unroll
    for (int i = 0; i < 5; ++i) {
        const int* rot = (i & 1) ? rotB : rotA;
#pragma unroll
        for (int j = 0; j < 4; ++j) {
            x0 += x1;
            x1 = (x1 << rot[j]) | (x1 >> (32 - rot[j]));
            x1 ^= x0;
        }
        x0 += ks[(i + 1) % 3];
        x1 += ks[(i + 2) % 3] + (uint32_t)(i + 1);
    }
    o0 = x0;
    o1 = x1;
}

// jax.random.uniform(...)*2-1, partitionable threefry: bits[j] = xor-fold of
// threefry(key, (0, j)).
__device__ inline float jax_uniform_pm1(uint32_t k0, uint32_t k1, uint32_t j) {
    uint32_t o0, o1;
    tf2x32(k0, k1, 0u, j, o0, o1);
    uint32_t bits = o0 ^ o1;
    float f = __uint_as_float((bits >> 9) | 0x3f800000u); // [1,2)
    return (f - 1.0f) * 2.0f - 1.0f;                      // [-1,1)
}

// XLA's f32 tanh rational approximation, non-contracted f32 ops.
__device__ inline float tanh_xla_f32(float x) {
    if (fabsf(x) < 0.0004f) return x;
    float xc = fminf(fmaxf(x, -9.0f), 9.0f);
    float x2 = __fmul_rn(xc, xc);
    float num = -2.76076847742355e-16f;
    num = __fadd_rn(__fmul_rn(num, x2), 2.00018790482477e-13f);
    num = __fadd_rn(__fmul_rn(num, x2), -8.60467152213735e-11f);
    num = __fadd_rn(__fmul_rn(num, x2), 5.12229709037114e-08f);
    num = __fadd_rn(__fmul_rn(num, x2), 1.48572235717979e-05f);
    num = __fadd_rn(__fmul_rn(num, x2), 6.37261928875436e-04f);
    num = __fadd_rn(__fmul_rn(num, x2), 4.89352455891786e-03f);
    num = __fmul_rn(num, xc);
    float den = 1.19825839466702e-06f;
    den = __fadd_rn(__fmul_rn(den, x2), 1.18534705686654e-04f);
    den = __fadd_rn(__fmul_rn(den, x2), 2.26843463243900e-03f);
    den = __fadd_rn(__fmul_rn(den, x2), 4.89352518554385e-03f);
    return __fdiv_rn(num, den);
}

__device__ inline float gibbs_decide(double acc, float h, float u) {
    float I32 = (float)(acc + (double)h);
    float t = tanh_xla_f32(I32);
    float d = __fadd_rn(t, -u);
    return (d > 0.0f) ? 1.0f : ((d < 0.0f) ? -1.0f : 0.0f);
}

struct SweepKeys { uint32_t v[16]; };  // [s]: k0a,k0b,k1a,k1b

// Barrier state in d_out (memory we provably own; overwritten by t_out at the
// very end): flags[i] at d_out[i*16] (one 64 B line per block), gen at d_out[4096].
__global__ __launch_bounds__(256) void zinit(uint32_t* p) {
    p[threadIdx.x * 16] = 0u;
    if (threadIdx.x == 0) p[4096] = 0u;
}

// Distributed-flag grid barrier: per-block release flag (no contended RMW),
// block 0 polls lane-parallel then broadcasts gen; spinners use relaxed loads
// + one acquire load on exit.
__device__ __forceinline__ void grid_sync(uint32_t* flags, uint32_t* gen, uint32_t k) {
    __syncthreads();
    const int tid = (int)threadIdx.x;
    if (tid == 0)   // release: L2 wb + flag store (own line -> parallel arrivals)
        __hip_atomic_store(&flags[blockIdx.x * 16], k, __ATOMIC_RELEASE,
                           __HIP_MEMORY_SCOPE_AGENT);
    if (blockIdx.x == 0 && tid < 64) {
        // wave 0: lane L polls flags[L], [L+64], [L+128], [L+192]
        for (;;) {
            bool mine = true;
#pragma unroll
            for (int i = 0; i < 4; ++i) {
                uint32_t v = __hip_atomic_load(&flags[(tid + i * 64) * 16],
                                               __ATOMIC_RELAXED, __HIP_MEMORY_SCOPE_AGENT);
                mine &= (v >= k);
            }
            if (__all(mine)) break;
            __builtin_amdgcn_s_sleep(1);
        }
        if (tid == 0)
            __hip_atomic_store(gen, k, __ATOMIC_RELEASE, __HIP_MEMORY_SCOPE_AGENT);
    }
    if (tid == 0) {
        while (__hip_atomic_load(gen, __ATOMIC_RELAXED, __HIP_MEMORY_SCOPE_AGENT) < k)
            __builtin_amdgcn_s_sleep(1);
        (void)__hip_atomic_load(gen, __ATOMIC_ACQUIRE, __HIP_MEMORY_SCOPE_AGENT);  // inv once
    }
    __syncthreads();
}

__global__ __launch_bounds__(256) void fused(const float* __restrict__ m_in,
                                             const float* __restrict__ J,
                                             const float* __restrict__ H,
                                             float* __restrict__ m_out,
                                             float* __restrict__ mt,
                                             SweepKeys keys) {
    uint32_t* flags = (uint32_t*)m_out;
    uint32_t* gen   = flags + 4096;
    uint32_t  bk    = 0;            // barrier ordinal (identical across blocks)
    __shared__ float  jc[800];      // J_CNN closure: jc[f*25+pos]
    __shared__ double red[4][64];
    const int tid  = (int)threadIdx.x;
    const int blk  = (int)blockIdx.x;
    const int lane = tid & 63;                 // lane = batch b
    const int wave = tid >> 6;
    const int gwid = blk * 4 + wave;           // 0..1023

    // ---- phase T_in: mt[node][b] = m[b][node]; stage closure into LDS ----
    for (int t = blk * 256 + tid; t < NN * BATCH; t += NB * 256)
        mt[t] = m_in[(size_t)(t & 63) * NN + (t >> 6)];
    for (int t = tid; t < 800; t += 256) {
        int f = t / 25, pos = t % 25;
        jc[t] = J[(size_t)(IMG_N + f * 144) * NN + (pos / 5) * IMGW + (pos % 5)];
    }
    grid_sync(flags, gen, ++bk);

    for (int s = 0; s < 4; ++s) {
        const uint32_t k0a = keys.v[s * 4 + 0], k0b = keys.v[s * 4 + 1];
        const uint32_t k1a = keys.v[s * 4 + 2], k1b = keys.v[s * 4 + 3];

        // ---- g0: blocks 0..49 -> out nodes; blocks 50..255 -> img pixels ----
        if (blk < 50) {
            const int o = blk;
            const float* Jrow = J + (size_t)(IMG_N + CNN_N + o) * NN + IMG_N;
            double a0 = 0.0, a1 = 0.0;
            const int k0i = wave * 1152;
#pragma unroll 4
            for (int k = 0; k < 1152; k += 2) {
                a0 += (double)Jrow[k0i + k]     * (double)mt[(IMG_N + k0i + k) * 64 + lane];
                a1 += (double)Jrow[k0i + k + 1] * (double)mt[(IMG_N + k0i + k + 1) * 64 + lane];
            }
            red[wave][lane] = a0 + a1;
            __syncthreads();
            if (wave == 0) {
                double a = ((red[0][lane] + red[1][lane]) + red[2][lane]) + red[3][lane];
                float u = jax_uniform_pm1(k0a, k0b, (uint32_t)(lane * G0SZ + IMG_N + o));
                mt[(IMG_N + CNN_N + o) * 64 + lane] =
                    gibbs_decide(a, H[IMG_N + CNN_N + o], u);
            }
        } else {
            const int iw = (blk - 50) * 4 + wave;  // 0..823
            for (int g = iw; g < IMG_N; g += 824) {
                int r = g / IMGW, c = g % IMGW;
                int pr_lo = (r >= 4) ? (r - 2) / 3 : 0;
                int pr_hi = r / 3; if (pr_hi > NPATCH - 1) pr_hi = NPATCH - 1;
                int pc_lo = (c >= 4) ? (c - 2) / 3 : 0;
                int pc_hi = c / 3; if (pc_hi > NPATCH - 1) pc_hi = NPATCH - 1;
                double acc = 0.0;
                for (int pr = pr_lo; pr <= pr_hi; ++pr) {
                    for (int pc = pc_lo; pc <= pc_hi; ++pc) {
                        int pos = (r - 3 * pr) * 5 + (c - 3 * pc);
                        int node0 = IMG_N + pr * NPATCH + pc;
#pragma unroll
                        for (int f = 0; f < 32; ++f)
                            acc += (double)jc[f * 25 + pos] *
                                   (double)mt[(node0 + f * 144) * 64 + lane];
                    }
                }
                float u = jax_uniform_pm1(k0a, k0b, (uint32_t)(lane * G0SZ + g));
                mt[g * 64 + lane] = gibbs_decide(acc, H[g], u);
            }
        }
        grid_sync(flags, gen, ++bk);

        // ---- g1: cnn nodes, wave-stride ----
        for (int cn = gwid; cn < CNN_N; cn += NB * 4) {
            int f = cn / 144;
            int p = cn - f * 144;
            int pr = p / NPATCH, pc = p - pr * NPATCH;
            int r0 = pr * 3, c0 = pc * 3;
            double acc = 0.0;
#pragma unroll
            for (int a = 0; a < 5; ++a) {
                int rowbase = (r0 + a) * IMGW + c0;
#pragma unroll
                for (int bb = 0; bb < 5; ++bb)
                    acc += (double)jc[f * 25 + a * 5 + bb] *
                           (double)mt[(rowbase + bb) * 64 + lane];
            }
            const float* Jo = J + (size_t)(IMG_N + cn) * NN + IMG_N + CNN_N;
#pragma unroll 10
            for (int o = 0; o < OUT_N; ++o)
                acc += (double)Jo[o] * (double)mt[(IMG_N + CNN_N + o) * 64 + lane];
            float u = jax_uniform_pm1(k1a, k1b, (uint32_t)(lane * G1SZ + cn));
            mt[(IMG_N + cn) * 64 + lane] = gibbs_decide(acc, H[IMG_N + cn], u);
        }
        grid_sync(flags, gen, ++bk);
    }

    // ---- T_out: m_out[b][node] = mt[node][b] (overwrites barrier words too) ----
    for (int t = blk * 256 + tid; t < NN * BATCH; t += NB * 256) {
        int b = t / NN, node = t - b * NN;
        m_out[t] = mt[node * 64 + b];
    }
}

extern "C" void kernel_launch(void* const* d_in, const int* in_sizes, int n_in,
                              void* d_out, int out_size, void* d_ws, size_t ws_size,
                              hipStream_t stream) {
    const float* m_in = (const float*)d_in[0];
    const float* J    = (const float*)d_in[1];
    const float* H    = (const float*)d_in[2];
    float* m_out = (float*)d_out;
    float* mt    = (float*)d_ws;  // [NN][64], 1.6 MB (ws_size proven >= this)

    // partitionable key chain: keys = split(key(1),4): keys[i]=threefry((0,1),(0,i))
    uint32_t K[4][2];
    for (int i = 0; i < 4; ++i)
        tf2x32(0u, 1u, 0u, (uint32_t)i, K[i][0], K[i][1]);
    SweepKeys keys;
    for (int s = 0; s < 4; ++s) {
        uint32_t k0a, k0b, k1a, k1b;
        tf2x32(K[s][0], K[s][1], 0u, 0u, k0a, k0b);  // k0 = split(keys[s])[0]
        tf2x32(K[s][0], K[s][1], 0u, 1u, k1a, k1b);  // k1 = split(keys[s])[1]
        keys.v[s * 4 + 0] = k0a; keys.v[s * 4 + 1] = k0b;
        keys.v[s * 4 + 2] = k1a; keys.v[s * 4 + 3] = k1b;
    }

    zinit<<<1, 256, 0, stream>>>((uint32_t*)d_out);
    fused<<<NB, 256, 0, stream>>>(m_in, J, H, m_out, mt, keys);
}